// Round 16
// baseline (81.594 us; speedup 1.0000x reference)
//
#include <hip/hip_runtime.h>
#include <hip/hip_bf16.h>

// ContrastiveLoss (NT-Xent): B=2048, D=256, T=0.5
// loss = mean_i [ -2*dot(zh_i, zh_pos(i)) + log( sum_j exp(2*dot(zh_i, zh_j)) - e^2 ) ]
// v10 = v9 with k_sim reshaped 1056x256t -> 528x512t, tiles in PARALLEL.
// Rationale: v7->v9 micro-opts all neutral; budget model (v5's direct k_sim=48
// + fill 42.5 inside window) puts k_sim at ~20us vs ~1.5us per-block critical
// path -> suspected workgroup-dispatch-rate bound (~20ns/WG * 1056). Halve WG
// count: waves 0-3 compute tile jc0, waves 4-7 tile jc1 (same row panel --
// panel tile-counts even, t0 even => pair never straddles). NO serial tiles
// (v5/v8 trap), 16 waves/CU kept (2 blocks/CU x 8 waves; v5/v8 had only 8/CU).
// Per-wave structure identical to v9: own-quarter-first staging overlap,
// per-wave plain-store col partials, XOR-swizzled global_load_lds staging,
// collision-free Prow/Pcol stores, zb2 pre-scaled 2*log2(e) -> exp2.

typedef __attribute__((ext_vector_type(8))) short short8;
typedef __attribute__((ext_vector_type(4))) float float4v;

#define NROWS 4096
#define DIM 256
#define NB 2048
#define TEMP_INV 2.0f
#define SCALE 2.8853900817779268f  // 2*log2(e)
#define NBLK 528                   // tile pairs; 1056 tiles total

static __device__ __forceinline__ unsigned short f2bf_rne(float f) {
    unsigned int x = __float_as_uint(f);
    unsigned int r = x + 0x7FFFu + ((x >> 16) & 1u);
    return (unsigned short)(r >> 16);
}

// K1: normalize pair (p, p+NB); zero Pall (1.5 MB) and out. grid 512 x 256.
__global__ __launch_bounds__(256) void k_norm(const float* __restrict__ zi,
                                              const float* __restrict__ zj,
                                              unsigned short* __restrict__ zb,
                                              unsigned short* __restrict__ zb2,
                                              float* __restrict__ pd,
                                              float4* __restrict__ pzero,
                                              float* __restrict__ out) {
    if (blockIdx.x == 0 && threadIdx.x == 0) *out = 0.0f;
    {
        int g = blockIdx.x * 256 + threadIdx.x;
        if (g < 98304) {
            float4 z; z.x = 0.f; z.y = 0.f; z.z = 0.f; z.w = 0.f;
            pzero[g] = z;
        }
    }
    int wave = threadIdx.x >> 6, lane = threadIdx.x & 63;
    int p = blockIdx.x * 4 + wave;  // pair index: rows p and p+NB
    float4 vi = *(const float4*)(zi + (size_t)p * DIM + lane * 4);
    float4 vj = *(const float4*)(zj + (size_t)p * DIM + lane * 4);
    float ssi = vi.x * vi.x + vi.y * vi.y + vi.z * vi.z + vi.w * vi.w;
    float ssj = vj.x * vj.x + vj.y * vj.y + vj.z * vj.z + vj.w * vj.w;
    float dij = vi.x * vj.x + vi.y * vj.y + vi.z * vj.z + vi.w * vj.w;
    #pragma unroll
    for (int off = 32; off > 0; off >>= 1) {
        ssi += __shfl_xor(ssi, off);
        ssj += __shfl_xor(ssj, off);
        dij += __shfl_xor(dij, off);
    }
    float si = 1.0f / fmaxf(sqrtf(ssi), 1e-12f);
    float sj = 1.0f / fmaxf(sqrtf(ssj), 1e-12f);
    ushort4 a, b;
    a.x = f2bf_rne(vi.x * si); a.y = f2bf_rne(vi.y * si);
    a.z = f2bf_rne(vi.z * si); a.w = f2bf_rne(vi.w * si);
    b.x = f2bf_rne(vj.x * sj); b.y = f2bf_rne(vj.y * sj);
    b.z = f2bf_rne(vj.z * sj); b.w = f2bf_rne(vj.w * sj);
    *(ushort4*)(zb + (size_t)p * DIM + lane * 4) = a;
    *(ushort4*)(zb + (size_t)(p + NB) * DIM + lane * 4) = b;
    float ki = si * SCALE, kj = sj * SCALE;
    ushort4 a2, b2;
    a2.x = f2bf_rne(vi.x * ki); a2.y = f2bf_rne(vi.y * ki);
    a2.z = f2bf_rne(vi.z * ki); a2.w = f2bf_rne(vi.w * ki);
    b2.x = f2bf_rne(vj.x * kj); b2.y = f2bf_rne(vj.y * kj);
    b2.z = f2bf_rne(vj.z * kj); b2.w = f2bf_rne(vj.w * kj);
    *(ushort4*)(zb2 + (size_t)p * DIM + lane * 4) = a2;
    *(ushort4*)(zb2 + (size_t)(p + NB) * DIM + lane * 4) = b2;
    if (lane == 0) pd[p] = dij * si * sj;
}

// K2: tile PAIR per 512-thread block; waves 0-3 -> tile jc0, waves 4-7 -> jc1.
// Tile decode (pair): t0 = 2*swb -> (ib, jc0 = 2*ib + rem), rem even, jc1=jc0+1.
__global__ __launch_bounds__(512, 4) void k_sim(const unsigned short* __restrict__ zb,
                                                const unsigned short* __restrict__ zb2,
                                                float* __restrict__ Prow,
                                                float* __restrict__ Pcol) {
    __shared__ __attribute__((aligned(1024))) short Bs[2][64 * 256];  // 64 KB
    __shared__ float csw[2][4][64];  // per-half, per-wave column partials

    // XCD-chunked swizzle (bijective: 528 = 8 * 66)
    int bid = blockIdx.x;
    int swb = (bid & 7) * 66 + (bid >> 3);
    int t0 = swb * 2;
    int rem = t0, ib = 0;
    while (rem >= 64 - 2 * ib) { rem -= 64 - 2 * ib; ib++; }
    int jc0 = 2 * ib + rem;  // within-panel offset even; pair stays in panel

    int tid = threadIdx.x, wave = tid >> 6, lane = tid & 63;
    int half = wave >> 2, wl = wave & 3;   // half: which tile; wl: wave-in-tile
    int jc = jc0 + half;
    bool do_col = (jc >= 2 * ib + 2);
    int m = lane & 15, q = lane >> 4;
    const short* zsB = (const short*)zb;
    const short* zsA = (const short*)zb2;
    int ibase = ib * 128 + wl * 32;
    int jbase = jc * 64;

    // Async-stage: wave (half,wl) stages rows [wl*16, wl*16+16) of strip jc
    // into Bs[half]. global_load_lds writes 1024B=2rows linearly; source slot
    // pre-swizzled (slot ^ (row&7)); read side applies the same XOR.
    {
        int s = lane & 31;      // 16B slot within row
        int rhalf = lane >> 5;  // 0 or 1
        #pragma unroll
        for (int c = 0; c < 8; c++) {
            int r = wl * 16 + c * 2 + rhalf;  // own 16-row band of own strip
            const short* gsrc = zsB + (size_t)(jbase + r) * DIM + ((s ^ (r & 7)) * 8);
            short* ldst = &Bs[half][(wl * 16 + c * 2) * 256];  // wave-uniform base
            __builtin_amdgcn_global_load_lds(
                (const __attribute__((address_space(1))) unsigned int*)gsrc,
                (__attribute__((address_space(3))) unsigned int*)ldst,
                16, 0, 0);
        }
    }

    // A fragments: A[m][k], m = lane&15, k = q*8 + t (verified 16x16x32 layout).
    // Waves wl and wl+4 load the same panel rows (L1/L2 hit on second).
    short8 A[2][8];
    #pragma unroll
    for (int t = 0; t < 2; t++) {
        const short* arow = zsA + (size_t)(ibase + t * 16 + m) * DIM + q * 8;
        #pragma unroll
        for (int kk = 0; kk < 8; kk++) A[t][kk] = *(const short8*)(arow + kk * 32);
    }

    // Drain OWN loads (vmcnt per-wave); own-quarter compute before the barrier.
    asm volatile("s_waitcnt vmcnt(0)" ::: "memory");

    float rowacc[2][4] = {{0.f, 0.f, 0.f, 0.f}, {0.f, 0.f, 0.f, 0.f}};
    int swz = m & 7;

    #pragma unroll
    for (int step = 0; step < 4; step++) {
        int jt = (wl + step) & 3;  // step 0: own staged rows (jt == wl)
        const short* brow = &Bs[half][(jt * 16 + m) * 256];
        float4v c0 = {0.f, 0.f, 0.f, 0.f};
        float4v c1 = {0.f, 0.f, 0.f, 0.f};
        #pragma unroll
        for (int kk = 0; kk < 8; kk++) {
            short8 b = *(const short8*)(brow + (((q + 4 * kk) ^ swz) * 8));
            c0 = __builtin_amdgcn_mfma_f32_16x16x32_bf16(A[0][kk], b, c0, 0, 0, 0);
            c1 = __builtin_amdgcn_mfma_f32_16x16x32_bf16(A[1][kk], b, c1, 0, 0, 0);
        }
        float csum = 0.0f;
        #pragma unroll
        for (int r = 0; r < 4; r++) {
            float e0 = __builtin_exp2f(c0[r]);
            float e1 = __builtin_exp2f(c1[r]);
            rowacc[0][r] += e0; rowacc[1][r] += e1;
            csum += e0 + e1;
        }
        if (do_col) {
            csum += __shfl_xor(csum, 16);
            csum += __shfl_xor(csum, 32);
            if (lane < 16) csw[half][wl][jt * 16 + m] = csum;
        }
        if (step == 0) __syncthreads();  // all 8 waves' staging complete after this
    }

    // row sums: reduce over 16 column-lanes, plain store into Prow[jc][row]
    #pragma unroll
    for (int t = 0; t < 2; t++) {
        #pragma unroll
        for (int r = 0; r < 4; r++) {
            float s = rowacc[t][r];
            s += __shfl_xor(s, 1);
            s += __shfl_xor(s, 2);
            s += __shfl_xor(s, 4);
            s += __shfl_xor(s, 8);
            if (m == 0) Prow[jc * NROWS + ibase + t * 16 + q * 4 + r] = s;
        }
    }
    __syncthreads();  // csw visible (uniform barrier; executed by all threads)
    if (tid < 128) {
        int h = tid >> 6, col = tid & 63;
        int jch = jc0 + h;
        if (jch >= 2 * ib + 2) {
            float c = csw[h][0][col] + csw[h][1][col] + csw[h][2][col] + csw[h][3][col];
            Pcol[ib * NROWS + jch * 64 + col] = c;
        }
    }
}

// K3: S_i = sum of 96 contiguous partial planes (Pall = Prow 0..63, Pcol 64..95);
// loss = mean log(S_i - e^2) - 2*pd[i%NB]. grid 64 x 256.
__global__ __launch_bounds__(256) void k_loss(const float* __restrict__ Pall,
                                              const float* __restrict__ pd,
                                              float* __restrict__ out) {
    __shared__ float red2[4][64];
    int tid = threadIdx.x;
    int t = tid & 63, quarter = tid >> 6;
    int row = blockIdx.x * 64 + t;
    float s = 0.0f;
    #pragma unroll
    for (int k = 0; k < 24; k++) {
        int p = quarter * 24 + k;
        s += Pall[(size_t)p * NROWS + row];
    }
    red2[quarter][t] = s;
    __syncthreads();
    if (tid < 64) {
        float tot = red2[0][t] + red2[1][t] + red2[2][t] + red2[3][t];
        const float E2 = 7.38905609893065f;  // exp(sim_ii) = e^2
        float term = logf(tot - E2) - TEMP_INV * pd[row & (NB - 1)];
        #pragma unroll
        for (int off = 32; off > 0; off >>= 1) term += __shfl_xor(term, off);
        if (t == 0) atomicAdd(out, term * (1.0f / NROWS));
    }
}

extern "C" void kernel_launch(void* const* d_in, const int* in_sizes, int n_in,
                              void* d_out, int out_size, void* d_ws, size_t ws_size,
                              hipStream_t stream) {
    const float* zi = (const float*)d_in[0];
    const float* zj = (const float*)d_in[1];
    float* out = (float*)d_out;
    char* ws = (char*)d_ws;
    unsigned short* zb  = (unsigned short*)ws;                          // 2 MB bf16 normalized
    unsigned short* zb2 = (unsigned short*)(ws + 2 * 1024 * 1024);      // 2 MB bf16 * 2log2e
    float* Pall = (float*)(ws + 4 * 1024 * 1024);                       // 96 planes x 4096 = 1.5 MB
    float* Prow = Pall;                                                 // planes 0..63 (by jc)
    float* Pcol = Pall + 64 * NROWS;                                    // planes 64..95 (by ib)
    float* pd   = (float*)(ws + 5 * 1024 * 1024 + 512 * 1024);          // 8 KB pos dots

    hipLaunchKernelGGL(k_norm, dim3(512), dim3(256), 0, stream,
                       zi, zj, zb, zb2, pd, (float4*)Pall, out);
    hipLaunchKernelGGL(k_sim, dim3(NBLK), dim3(512), 0, stream, zb, zb2, Prow, Pcol);
    hipLaunchKernelGGL(k_loss, dim3(64), dim3(256), 0, stream, Pall, pd, out);
}

// Round 18
// 77.920 us; speedup vs baseline: 1.0472x; 1.0472x over previous
//
#include <hip/hip_runtime.h>
#include <hip/hip_bf16.h>

// ContrastiveLoss (NT-Xent): B=2048, D=256, T=0.5
// loss = mean_i [ -2*dot(zh_i, zh_pos(i)) + log( sum_j exp(2*dot(zh_i, zh_j)) - e^2 ) ]
// v9 (FINAL): best measured = 78.10us (round 13; passed, absmax 0). Ledger:
// v0 78.5 / v1 96.7 / v3 82.1 / v5 105.4 / v6 80.9 / v7 78.2 / v8 101.9 /
// v9 78.1 / v10 81.6. Falsified: S-atomic contention (v6 neutral),
// staging-drain stall (v9 own-quarter neutral), WG-dispatch-rate (v10
// regressed), serial multi-tile & fused structures (v1/v5/v8 all ~+20us),
// cooperative launch (no-op in harness). Timed window contains a fixed
// ~42.5us 256MiB workspace re-poison fill + ~7us launch gaps; controllable
// portion ~35us (k_sim ~20 latency-floor, k_norm ~4, k_loss ~2).
// Structure: 1056 one-tile 128x64 upper-tri blocks, __launch_bounds__(256,4),
// XCD-chunked bijective swizzle (1056=8*132), B strip staged via
// global_load_lds w=16 (XOR-swizzled source + swizzled ds_read, bank-conflict
// floor), own-quarter-first compute under per-wave vmcnt, collision-free
// Prow/Pcol partial-sum stores (zero global atomics in k_sim), zb2 pre-scaled
// by 2*log2(e) so exp(2*sim) = exp2(dot) -> bare v_exp_f32.

typedef __attribute__((ext_vector_type(8))) short short8;
typedef __attribute__((ext_vector_type(4))) float float4v;

#define NROWS 4096
#define DIM 256
#define NB 2048
#define TEMP_INV 2.0f
#define SCALE 2.8853900817779268f  // 2*log2(e)
#define NTILES 1056  // sum_{ib=0}^{31} (64 - 2*ib) upper-triangular 128x64 tiles

static __device__ __forceinline__ unsigned short f2bf_rne(float f) {
    unsigned int x = __float_as_uint(f);
    unsigned int r = x + 0x7FFFu + ((x >> 16) & 1u);
    return (unsigned short)(r >> 16);
}

// K1: normalize pair (p, p+NB); zero Pall (1.5 MB) and out. grid 512 x 256.
__global__ __launch_bounds__(256) void k_norm(const float* __restrict__ zi,
                                              const float* __restrict__ zj,
                                              unsigned short* __restrict__ zb,
                                              unsigned short* __restrict__ zb2,
                                              float* __restrict__ pd,
                                              float4* __restrict__ pzero,
                                              float* __restrict__ out) {
    if (blockIdx.x == 0 && threadIdx.x == 0) *out = 0.0f;
    // zero Pall = 96 planes x 4096 floats = 98304 float4s across 131072 threads
    {
        int g = blockIdx.x * 256 + threadIdx.x;
        if (g < 98304) {
            float4 z; z.x = 0.f; z.y = 0.f; z.z = 0.f; z.w = 0.f;
            pzero[g] = z;
        }
    }
    int wave = threadIdx.x >> 6, lane = threadIdx.x & 63;
    int p = blockIdx.x * 4 + wave;  // pair index: rows p and p+NB
    float4 vi = *(const float4*)(zi + (size_t)p * DIM + lane * 4);
    float4 vj = *(const float4*)(zj + (size_t)p * DIM + lane * 4);
    float ssi = vi.x * vi.x + vi.y * vi.y + vi.z * vi.z + vi.w * vi.w;
    float ssj = vj.x * vj.x + vj.y * vj.y + vj.z * vj.z + vj.w * vj.w;
    float dij = vi.x * vj.x + vi.y * vj.y + vi.z * vj.z + vi.w * vj.w;
    #pragma unroll
    for (int off = 32; off > 0; off >>= 1) {
        ssi += __shfl_xor(ssi, off);
        ssj += __shfl_xor(ssj, off);
        dij += __shfl_xor(dij, off);
    }
    float si = 1.0f / fmaxf(sqrtf(ssi), 1e-12f);
    float sj = 1.0f / fmaxf(sqrtf(ssj), 1e-12f);
    ushort4 a, b;
    a.x = f2bf_rne(vi.x * si); a.y = f2bf_rne(vi.y * si);
    a.z = f2bf_rne(vi.z * si); a.w = f2bf_rne(vi.w * si);
    b.x = f2bf_rne(vj.x * sj); b.y = f2bf_rne(vj.y * sj);
    b.z = f2bf_rne(vj.z * sj); b.w = f2bf_rne(vj.w * sj);
    *(ushort4*)(zb + (size_t)p * DIM + lane * 4) = a;
    *(ushort4*)(zb + (size_t)(p + NB) * DIM + lane * 4) = b;
    float ki = si * SCALE, kj = sj * SCALE;
    ushort4 a2, b2;
    a2.x = f2bf_rne(vi.x * ki); a2.y = f2bf_rne(vi.y * ki);
    a2.z = f2bf_rne(vi.z * ki); a2.w = f2bf_rne(vi.w * ki);
    b2.x = f2bf_rne(vj.x * kj); b2.y = f2bf_rne(vj.y * kj);
    b2.z = f2bf_rne(vj.z * kj); b2.w = f2bf_rne(vj.w * kj);
    *(ushort4*)(zb2 + (size_t)p * DIM + lane * 4) = a2;
    *(ushort4*)(zb2 + (size_t)(p + NB) * DIM + lane * 4) = b2;
    if (lane == 0) pd[p] = dij * si * sj;
}

// K2: one upper-triangular 128x64 exp2-tile per block; partial-sum stores.
// Tile decode: ib in [0,32), jc in [2*ib, 64).
__global__ __launch_bounds__(256, 4) void k_sim(const unsigned short* __restrict__ zb,
                                                const unsigned short* __restrict__ zb2,
                                                float* __restrict__ Prow,
                                                float* __restrict__ Pcol) {
    __shared__ __attribute__((aligned(1024))) short Bs[64 * 256];  // 32 KB linear rows
    __shared__ float csw[4][64];  // per-wave column partials (plain stores)
    // XCD-chunked swizzle (bijective: 1056 % 8 == 0, chunk = 132): consecutive
    // tiles (sharing an A row-panel) land on the same XCD's L2.
    int bid = blockIdx.x;
    int swb = (bid & 7) * 132 + (bid >> 3);
    int rem = swb, ib = 0;
    while (rem >= 64 - 2 * ib) { rem -= 64 - 2 * ib; ib++; }
    int jc = 2 * ib + rem;
    bool do_col = (jc >= 2 * ib + 2);

    int tid = threadIdx.x, wave = tid >> 6, lane = tid & 63;
    int m = lane & 15, q = lane >> 4;
    const short* zsB = (const short*)zb;
    const short* zsA = (const short*)zb2;
    int ibase = ib * 128 + wave * 32;
    int jbase = jc * 64;

    // Async-stage 64 B-rows (512B each) into LDS. Each global_load_lds writes
    // 1024B = 2 rows linearly (lane -> base + lane*16). Source slot pre-swizzled
    // (slot ^ (row&7)); read side applies the same XOR.
    // NOTE: wave w stages exactly rows [w*16, w*16+16) -- own-quarter property.
    {
        int s = lane & 31;      // 16B slot within row
        int rhalf = lane >> 5;  // 0 or 1
        #pragma unroll
        for (int c = 0; c < 8; c++) {
            int r = wave * 16 + c * 2 + rhalf;  // local row (own 16-row band)
            const short* gsrc = zsB + (size_t)(jbase + r) * DIM + ((s ^ (r & 7)) * 8);
            short* ldst = &Bs[(wave * 16 + c * 2) * 256];  // wave-uniform base
            __builtin_amdgcn_global_load_lds(
                (const __attribute__((address_space(1))) unsigned int*)gsrc,
                (__attribute__((address_space(3))) unsigned int*)ldst,
                16, 0, 0);
        }
    }

    // A fragments: A[m][k], m = lane&15, k = q*8 + t  (verified 16x16x32 layout)
    short8 A[2][8];
    #pragma unroll
    for (int t = 0; t < 2; t++) {
        const short* arow = zsA + (size_t)(ibase + t * 16 + m) * DIM + q * 8;
        #pragma unroll
        for (int kk = 0; kk < 8; kk++) A[t][kk] = *(const short8*)(arow + kk * 32);
    }

    // Drain OWN loads only (vmcnt is per-wave); own-quarter compute can start
    // before the block barrier -- other waves' staging completes meanwhile.
    asm volatile("s_waitcnt vmcnt(0)" ::: "memory");

    float rowacc[2][4] = {{0.f, 0.f, 0.f, 0.f}, {0.f, 0.f, 0.f, 0.f}};
    int swz = m & 7;

    #pragma unroll
    for (int step = 0; step < 4; step++) {
        int jt = (wave + step) & 3;  // step 0: own staged rows (jt == wave)
        const short* brow = &Bs[(jt * 16 + m) * 256];
        float4v c0 = {0.f, 0.f, 0.f, 0.f};
        float4v c1 = {0.f, 0.f, 0.f, 0.f};
        #pragma unroll
        for (int kk = 0; kk < 8; kk++) {
            short8 b = *(const short8*)(brow + (((q + 4 * kk) ^ swz) * 8));
            c0 = __builtin_amdgcn_mfma_f32_16x16x32_bf16(A[0][kk], b, c0, 0, 0, 0);
            c1 = __builtin_amdgcn_mfma_f32_16x16x32_bf16(A[1][kk], b, c1, 0, 0, 0);
        }
        float csum = 0.0f;
        #pragma unroll
        for (int r = 0; r < 4; r++) {
            float e0 = __builtin_exp2f(c0[r]);
            float e1 = __builtin_exp2f(c1[r]);
            rowacc[0][r] += e0; rowacc[1][r] += e1;
            csum += e0 + e1;
        }
        if (do_col) {
            // column jt*16 + m: this wave's 32-row partial, plain store
            csum += __shfl_xor(csum, 16);
            csum += __shfl_xor(csum, 32);
            if (lane < 16) csw[wave][jt * 16 + m] = csum;
        }
        if (step == 0) __syncthreads();  // all waves' staging complete after this
    }

    // row sums: reduce over 16 column-lanes, plain store into Prow[jc][row]
    #pragma unroll
    for (int t = 0; t < 2; t++) {
        #pragma unroll
        for (int r = 0; r < 4; r++) {
            float s = rowacc[t][r];
            s += __shfl_xor(s, 1);
            s += __shfl_xor(s, 2);
            s += __shfl_xor(s, 4);
            s += __shfl_xor(s, 8);
            if (m == 0) Prow[jc * NROWS + ibase + t * 16 + q * 4 + r] = s;
        }
    }
    if (do_col) {
        __syncthreads();  // all csw writes visible
        if (tid < 64) {
            float c = csw[0][tid] + csw[1][tid] + csw[2][tid] + csw[3][tid];
            Pcol[ib * NROWS + jbase + tid] = c;
        }
    }
}

// K3: S_i = sum of 96 contiguous partial planes (Pall = Prow planes 0..63,
// Pcol planes 64..95); loss = mean log(S_i - e^2) - 2*pd[i%NB]. grid 64 x 256:
// block handles 64 rows; 4 plane-quarters per row combined in LDS.
__global__ __launch_bounds__(256) void k_loss(const float* __restrict__ Pall,
                                              const float* __restrict__ pd,
                                              float* __restrict__ out) {
    __shared__ float red2[4][64];
    int tid = threadIdx.x;
    int t = tid & 63, quarter = tid >> 6;
    int row = blockIdx.x * 64 + t;
    float s = 0.0f;
    #pragma unroll
    for (int k = 0; k < 24; k++) {
        int p = quarter * 24 + k;
        s += Pall[(size_t)p * NROWS + row];
    }
    red2[quarter][t] = s;
    __syncthreads();
    if (tid < 64) {
        float tot = red2[0][t] + red2[1][t] + red2[2][t] + red2[3][t];
        const float E2 = 7.38905609893065f;  // exp(sim_ii) = e^2
        float term = logf(tot - E2) - TEMP_INV * pd[row & (NB - 1)];
        #pragma unroll
        for (int off = 32; off > 0; off >>= 1) term += __shfl_xor(term, off);
        if (t == 0) atomicAdd(out, term * (1.0f / NROWS));
    }
}

extern "C" void kernel_launch(void* const* d_in, const int* in_sizes, int n_in,
                              void* d_out, int out_size, void* d_ws, size_t ws_size,
                              hipStream_t stream) {
    const float* zi = (const float*)d_in[0];
    const float* zj = (const float*)d_in[1];
    float* out = (float*)d_out;
    char* ws = (char*)d_ws;
    unsigned short* zb  = (unsigned short*)ws;                          // 2 MB bf16 normalized
    unsigned short* zb2 = (unsigned short*)(ws + 2 * 1024 * 1024);      // 2 MB bf16 * 2log2e
    float* Pall = (float*)(ws + 4 * 1024 * 1024);                       // 96 planes x 4096 = 1.5 MB
    float* Prow = Pall;                                                 // planes 0..63 (by jc)
    float* Pcol = Pall + 64 * NROWS;                                    // planes 64..95 (by ib)
    float* pd   = (float*)(ws + 5 * 1024 * 1024 + 512 * 1024);          // 8 KB pos dots

    hipLaunchKernelGGL(k_norm, dim3(512), dim3(256), 0, stream,
                       zi, zj, zb, zb2, pd, (float4*)Pall, out);
    hipLaunchKernelGGL(k_sim, dim3(NTILES), dim3(256), 0, stream, zb, zb2, Prow, Pcol);
    hipLaunchKernelGGL(k_loss, dim3(64), dim3(256), 0, stream, Pall, pd, out);
}